// Round 1
// baseline (1114.219 us; speedup 1.0000x reference)
//
#include <hip/hip_runtime.h>
#include <hip/hip_bf16.h>

// AWQ W4A16 linear: out[m,o] = sum_k x[m,k] * (q[o,k]*s[g,o] - z[g,o]), g=k/128
// M=4096, K=8192, O=8192.
// Two-pass: (1) dequant W -> bf16 [O,K] in ws, cvt x -> bf16 [M,K] in ws
//           (2) bf16 MFMA GEMM (m97 structure: 128x128 tile, BK=64,
//               global_load_lds width=16, 2-barrier loop), f32 out.

typedef __bf16 bf16x8 __attribute__((ext_vector_type(8)));
typedef float f32x4 __attribute__((ext_vector_type(4)));
typedef unsigned short ushort8 __attribute__((ext_vector_type(8)));

#define BM 128
#define BN 128
#define BK 64

__device__ __forceinline__ unsigned short f32_to_bf16(float f) {
  unsigned int u = __float_as_uint(f);
  u += 0x7FFFu + ((u >> 16) & 1u);  // RNE
  return (unsigned short)(u >> 16);
}

// Pass 1a: qweight [O, K/2] int32 (one byte each, low nibble = even k) -> W bf16 [O,K]
__global__ void dequant_kernel(const int* __restrict__ qw,
                               const float* __restrict__ scales,  // [K/128, O]
                               const float* __restrict__ zeros,   // [K/128, O]
                               unsigned short* __restrict__ W,
                               int O, int K) {
  const int Khalf = K >> 1;
  const long total4 = (long)O * Khalf / 4;  // 4 int32 per thread-iter
  const long stride = (long)gridDim.x * blockDim.x;
  for (long idx = (long)blockIdx.x * blockDim.x + threadIdx.x; idx < total4; idx += stride) {
    const long e0 = idx * 4;                 // int32 element index
    const int o = (int)(e0 / Khalf);
    const int j0 = (int)(e0 % Khalf);
    const int g = j0 >> 6;                   // 64 int32 = 128 k = one group
    const float s = scales[(long)g * O + o];
    const float z = zeros[(long)g * O + o];
    const int4 q = *reinterpret_cast<const int4*>(qw + e0);
    const int qv[4] = {q.x, q.y, q.z, q.w};
    ushort8 out;
#pragma unroll
    for (int i = 0; i < 4; ++i) {
      out[2 * i]     = f32_to_bf16((float)(qv[i] & 0xF) * s - z);
      out[2 * i + 1] = f32_to_bf16((float)((qv[i] >> 4) & 0xF) * s - z);
    }
    *reinterpret_cast<ushort8*>(W + e0 * 2) = out;
  }
}

// Pass 1b: x f32 [M,K] -> bf16
__global__ void cvt_x_kernel(const float* __restrict__ x,
                             unsigned short* __restrict__ xb, long n8) {
  const long stride = (long)gridDim.x * blockDim.x;
  for (long i = (long)blockIdx.x * blockDim.x + threadIdx.x; i < n8; i += stride) {
    const float4 a = *reinterpret_cast<const float4*>(x + i * 8);
    const float4 b = *reinterpret_cast<const float4*>(x + i * 8 + 4);
    ushort8 o;
    o[0] = f32_to_bf16(a.x); o[1] = f32_to_bf16(a.y);
    o[2] = f32_to_bf16(a.z); o[3] = f32_to_bf16(a.w);
    o[4] = f32_to_bf16(b.x); o[5] = f32_to_bf16(b.y);
    o[6] = f32_to_bf16(b.z); o[7] = f32_to_bf16(b.w);
    *reinterpret_cast<ushort8*>(xb + i * 8) = o;
  }
}

#define GLOAD16(g, l)                                                  \
  __builtin_amdgcn_global_load_lds(                                    \
      (const __attribute__((address_space(1))) void*)(g),              \
      (__attribute__((address_space(3))) void*)(l), 16, 0, 0)

// Pass 2: C[M,N] = A[M,K] * B[N,K]^T, all bf16 in, f32 out.
// 256 threads = 4 waves (2x2), each wave owns a 64x64 sub-tile (4x4 frags of 16x16).
__global__ __launch_bounds__(256) void gemm_kernel(
    const unsigned short* __restrict__ A,   // [M,K] bf16 bits
    const unsigned short* __restrict__ B,   // [N,K] bf16 bits
    float* __restrict__ C,                  // [M,N] f32
    int M, int N, int K) {
  __shared__ unsigned short lsA[BM * BK];   // 16 KB
  __shared__ unsigned short lsB[BN * BK];   // 16 KB

  const int t = threadIdx.x;
  const int w = t >> 6;
  const int l = t & 63;
  const int wr = w >> 1, wc = w & 1;        // wave grid 2x2
  const int lrow = l & 15, lgrp = l >> 4;   // MFMA lane decomposition

  const long bm0 = (long)blockIdx.y * BM;
  const long bn0 = (long)blockIdx.x * BN;

  // staging: chunk c = t + 256*i covers 16B; row = c>>3, 16B-col = c&7
  const char* gA = (const char*)(A + (bm0 + (t >> 3)) * (long)K) + (t & 7) * 16;
  const char* gB = (const char*)(B + (bn0 + (t >> 3)) * (long)K) + (t & 7) * 16;
  const long rstep = (long)32 * K * 2;      // 32 rows, bytes

  char* lA0 = (char*)&lsA[0] + t * 16;
  char* lB0 = (char*)&lsB[0] + t * 16;

  f32x4 acc[4][4] = {};

  for (int k0 = 0; k0 < K; k0 += BK) {
#pragma unroll
    for (int i = 0; i < 4; ++i) {
      GLOAD16(gA + i * rstep, lA0 + i * 4096);
      GLOAD16(gB + i * rstep, lB0 + i * 4096);
    }
    gA += BK * 2;
    gB += BK * 2;
    __syncthreads();   // drains vmcnt -> LDS tiles ready
#pragma unroll
    for (int s = 0; s < 2; ++s) {
      bf16x8 af[4], bfr[4];
#pragma unroll
      for (int i = 0; i < 4; ++i)
        af[i] = *reinterpret_cast<const bf16x8*>(
            &lsA[(wr * 64 + i * 16 + lrow) * BK + s * 32 + lgrp * 8]);
#pragma unroll
      for (int j = 0; j < 4; ++j)
        bfr[j] = *reinterpret_cast<const bf16x8*>(
            &lsB[(wc * 64 + j * 16 + lrow) * BK + s * 32 + lgrp * 8]);
#pragma unroll
      for (int i = 0; i < 4; ++i)
#pragma unroll
        for (int j = 0; j < 4; ++j)
          acc[i][j] = __builtin_amdgcn_mfma_f32_16x16x32_bf16(
              af[i], bfr[j], acc[i][j], 0, 0, 0);
    }
    __syncthreads();   // protect LDS before next stage
  }

  // epilogue: C/D layout col=lane&15, row=(lane>>4)*4+reg  [m89/m91 verified]
#pragma unroll
  for (int i = 0; i < 4; ++i)
#pragma unroll
    for (int j = 0; j < 4; ++j)
#pragma unroll
      for (int r = 0; r < 4; ++r) {
        const long row = bm0 + wr * 64 + i * 16 + lgrp * 4 + r;
        const long col = bn0 + wc * 64 + j * 16 + lrow;
        C[row * N + col] = acc[i][j][r];
      }
}

extern "C" void kernel_launch(void* const* d_in, const int* in_sizes, int n_in,
                              void* d_out, int out_size, void* d_ws, size_t ws_size,
                              hipStream_t stream) {
  const float* x = (const float*)d_in[0];        // [M,K] f32
  const int* qw = (const int*)d_in[1];           // [O,K/2] int32
  const float* wsc = (const float*)d_in[2];      // [K/128,O] f32
  const float* wz = (const float*)d_in[3];       // [K/128,O] f32
  float* out = (float*)d_out;                    // [M,O] f32

  const int M = 4096, K = 8192, O = 8192;

  unsigned short* Wb = (unsigned short*)d_ws;            // O*K bf16 = 134 MB
  unsigned short* Xb = Wb + (size_t)O * K;               // M*K bf16 = 67 MB

  dequant_kernel<<<2048, 256, 0, stream>>>(qw, wsc, wz, Wb, O, K);
  cvt_x_kernel<<<2048, 256, 0, stream>>>(x, Xb, (long)M * K / 8);

  dim3 grid(O / BN, M / BM);
  gemm_kernel<<<grid, 256, 0, stream>>>(Xb, Wb, out, M, O, K);
}

// Round 2
// 768.423 us; speedup vs baseline: 1.4500x; 1.4500x over previous
//
#include <hip/hip_runtime.h>
#include <hip/hip_bf16.h>

// AWQ W4A16: out[m,o] = sum_k x[m,k] * (q[o,k]*s[g,o] - z[g,o]),  g = k/128
// M=4096, K=8192, O=8192.
// Pass 1: dequant W -> bf16 [O,K] (pow2 shifts, no 64-bit div), cvt x -> bf16.
// Pass 2: 256x256 8-phase bf16 MFMA GEMM (T2 xor-swizzle + T3/T4 counted
//         vmcnt(6) + T5 setprio), 8 waves (2Mx4N), 128 KiB dbuf LDS.

typedef __bf16 bf16x8 __attribute__((ext_vector_type(8)));
typedef float f32x4 __attribute__((ext_vector_type(4)));
typedef unsigned short ushort8 __attribute__((ext_vector_type(8)));

#define Mdim 4096
#define Kdim 8192
#define Odim 8192
#define BM 256
#define BN 256
#define BK 64
#define K2 (Kdim * 2)     // bytes per logical row of A/B
#define TILEB (BK * 2)    // 128 bytes per row per K-tile
#define NT (Kdim / BK)    // 128 K-tiles

__device__ __forceinline__ unsigned short f32_to_bf16(float f) {
  unsigned int u = __float_as_uint(f);
  u += 0x7FFFu + ((u >> 16) & 1u);  // RNE
  return (unsigned short)(u >> 16);
}

// ---------- Pass 1a: qweight [O, K/2] int32 bytes -> W bf16 [O,K] ----------
__global__ void dequant_kernel(const int* __restrict__ qw,
                               const float* __restrict__ scales,  // [K/128, O]
                               const float* __restrict__ zeros,   // [K/128, O]
                               unsigned short* __restrict__ W) {
  const long total4 = (long)Odim * (Kdim / 2) / 4;  // 4 int32 per iter
  const long stride = (long)gridDim.x * blockDim.x;
  for (long idx = (long)blockIdx.x * blockDim.x + threadIdx.x; idx < total4;
       idx += stride) {
    const int o = (int)(idx >> 10);    // (K/2)/4 = 1024 quads per row
    const int jq = (int)(idx & 1023);
    const int g = jq >> 4;             // 16 quads = 128 k = one group
    const float s = scales[(long)g * Odim + o];
    const float z = zeros[(long)g * Odim + o];
    const int4 q = *reinterpret_cast<const int4*>(qw + (idx << 2));
    const int qv[4] = {q.x, q.y, q.z, q.w};
    ushort8 out;
#pragma unroll
    for (int i = 0; i < 4; ++i) {
      out[2 * i] = f32_to_bf16((float)(qv[i] & 0xF) * s - z);
      out[2 * i + 1] = f32_to_bf16((float)((qv[i] >> 4) & 0xF) * s - z);
    }
    *reinterpret_cast<ushort8*>(W + (idx << 3)) = out;
  }
}

// ---------- Pass 1b: x f32 [M,K] -> bf16 ----------
__global__ void cvt_x_kernel(const float* __restrict__ x,
                             unsigned short* __restrict__ xb, long n8) {
  const long stride = (long)gridDim.x * blockDim.x;
  for (long i = (long)blockIdx.x * blockDim.x + threadIdx.x; i < n8;
       i += stride) {
    const float4 a = *reinterpret_cast<const float4*>(x + i * 8);
    const float4 b = *reinterpret_cast<const float4*>(x + i * 8 + 4);
    ushort8 o;
    o[0] = f32_to_bf16(a.x); o[1] = f32_to_bf16(a.y);
    o[2] = f32_to_bf16(a.z); o[3] = f32_to_bf16(a.w);
    o[4] = f32_to_bf16(b.x); o[5] = f32_to_bf16(b.y);
    o[6] = f32_to_bf16(b.z); o[7] = f32_to_bf16(b.w);
    *reinterpret_cast<ushort8*>(xb + i * 8) = o;
  }
}

// ---------- Pass 2: 8-phase 256^2 GEMM ----------
#define GLOAD16(g, l)                                                 \
  __builtin_amdgcn_global_load_lds(                                   \
      (const __attribute__((address_space(1))) void*)(g),             \
      (__attribute__((address_space(3))) void*)(l), 16, 0, 0)

#define BAR() __builtin_amdgcn_s_barrier()
#define WAIT_VM6() asm volatile("s_waitcnt vmcnt(6)" ::: "memory")

__global__ __launch_bounds__(512, 2) void gemm_kernel(
    const unsigned short* __restrict__ A,   // [M,K] bf16 bits (x)
    const unsigned short* __restrict__ B,   // [O,K] bf16 bits (W)
    float* __restrict__ C) {                // [M,O] f32
  __shared__ unsigned short lsA[2][BM][BK];  // 64 KB
  __shared__ unsigned short lsB[2][BN][BK];  // 64 KB

  const int t = threadIdx.x;
  const int l = t & 63;
  const int wid = t >> 6;
  const int wr = wid >> 2;   // 0..1  (M)
  const int wc = wid & 3;    // 0..3  (N)
  const int lrow = l & 15;
  const int lgrp = l >> 4;

  // bijective XCD swizzle (nwg=512, 512%8==0): XCD x gets contiguous s-range
  const int bgrid = (Mdim / BM) * (Odim / BN);  // 512
  const int s = (blockIdx.x & 7) * (bgrid >> 3) + (blockIdx.x >> 3);
  const int bx = s & (Odim / BN - 1);  // 0..31 (N)
  const int by = s >> 5;               // 0..15 (M)
  const long bm0 = (long)by * BM;
  const long bn0 = (long)bx * BN;

  // ---- staging addressing (pre-swizzled global source, linear LDS dest) ----
  const int tdiv8 = t >> 3;                        // 0..63
  const int pc = (t & 7) << 4;                     // physical 16B chunk
  const int px = pc ^ ((tdiv8 & 7) << 4);          // inverse-swizzled col
  const int rowA0 = tdiv8;                         // A rows 0..63 (round0)
  const int rowB0 = ((tdiv8 >> 5) << 6) + (tdiv8 & 31);  // B strips

  const char* gA0 = (const char*)A + (size_t)(bm0 + rowA0) * K2 + px;
  const char* gB0 = (const char*)B + (size_t)(bn0 + rowB0) * K2 + px;
  char* lA0 = (char*)&lsA[0][0][0] + rowA0 * 128 + pc;
  char* lB0 = (char*)&lsB[0][0][0] + rowB0 * 128 + pc;

  // A-half mh: rows {mh*64..mh*64+63} U {mh*64+128..}; 2 gloads per thread
#define STAGE_A(mh, kt, buf)                                          \
  do {                                                                \
    const char* _s = gA0 + (size_t)(mh) * (64 * K2) + (size_t)(kt)*TILEB; \
    char* _d = lA0 + (buf)*32768 + (mh)*8192;                         \
    GLOAD16(_s, _d);                                                  \
    GLOAD16(_s + (size_t)128 * K2, _d + 16384);                       \
  } while (0)

  // B-half nh: rows U_wc {wc*64+nh*32 .. +31}
#define STAGE_B(nh, kt, buf)                                          \
  do {                                                                \
    const char* _s = gB0 + (size_t)(nh) * (32 * K2) + (size_t)(kt)*TILEB; \
    char* _d = lB0 + (buf)*32768 + (nh)*4096;                         \
    GLOAD16(_s, _d);                                                  \
    GLOAD16(_s + (size_t)128 * K2, _d + 16384);                       \
  } while (0)

  // ---- fragment reads (swizzled: row&7 == l&7 for all frags) ----
  const int rA = wr * 128 + lrow;
  const int rB = wc * 64 + lrow;
  const int cu0 = (((lgrp << 4)) ^ ((l & 7) << 4)) >> 1;        // ks=0, ushorts
  const int cu1 = ((64 + (lgrp << 4)) ^ ((l & 7) << 4)) >> 1;   // ks=1
  const unsigned short* lsAp = &lsA[0][0][0];
  const unsigned short* lsBp = &lsB[0][0][0];

  f32x4 acc[8][4] = {};
  bf16x8 af[4][2], b0[2][2], b1[2][2];

#define LDA(mh, buf)                                                  \
  do {                                                                \
    const unsigned short* _p =                                        \
        lsAp + (buf)*16384 + (size_t)(rA + (mh)*64) * 64;             \
    _Pragma("unroll") for (int i = 0; i < 4; ++i) {                   \
      af[i][0] = *(const bf16x8*)(_p + i * 1024 + cu0);               \
      af[i][1] = *(const bf16x8*)(_p + i * 1024 + cu1);               \
    }                                                                 \
  } while (0)

#define LDB(nh, buf, breg)                                            \
  do {                                                                \
    const unsigned short* _p =                                        \
        lsBp + (buf)*16384 + (size_t)(rB + (nh)*32) * 64;             \
    _Pragma("unroll") for (int j = 0; j < 2; ++j) {                   \
      breg[j][0] = *(const bf16x8*)(_p + j * 1024 + cu0);             \
      breg[j][1] = *(const bf16x8*)(_p + j * 1024 + cu1);             \
    }                                                                 \
  } while (0)

#define MFMA_Q(mh, nh, breg)                                          \
  do {                                                                \
    __builtin_amdgcn_s_setprio(1);                                    \
    _Pragma("unroll") for (int i = 0; i < 4; ++i)                     \
    _Pragma("unroll") for (int j = 0; j < 2; ++j)                     \
    _Pragma("unroll") for (int ks = 0; ks < 2; ++ks)                  \
        acc[(mh)*4 + i][(nh)*2 + j] =                                 \
            __builtin_amdgcn_mfma_f32_16x16x32_bf16(                  \
                af[i][ks], breg[j][ks], acc[(mh)*4 + i][(nh)*2 + j],  \
                0, 0, 0);                                             \
    __builtin_amdgcn_s_setprio(0);                                    \
  } while (0)

  // ---- prologue: tile0 (4 HTs) + tile1 first 3 HTs; vmcnt(6) => tile0 in ----
  STAGE_B(0, 0, 0); STAGE_A(0, 0, 0); STAGE_B(1, 0, 0); STAGE_A(1, 0, 0);
  STAGE_B(0, 1, 1); STAGE_A(0, 1, 1); STAGE_B(1, 1, 1);
  WAIT_VM6();
  BAR();

  // ---- main loop: iteration j computes tiles 2j (buf0), 2j+1 (buf1) ----
#pragma unroll 1
  for (int j = 0; j < NT / 2; ++j) {
    const int u1 = 2 * j + 1;
    const int u2 = (2 * j + 2 < NT) ? 2 * j + 2 : NT - 1;  // clamp: garbage
    const int u3 = (2 * j + 3 < NT) ? 2 * j + 3 : NT - 1;  // never read

    // phase 0: Q00 of tile 2j | stage S0 = A1(u1)->buf1
    LDA(0, 0); LDB(0, 0, b0);
    STAGE_A(1, u1, 1);
    BAR();
    MFMA_Q(0, 0, b0);
    BAR();
    // phase 1: Q01 (reuse af) | S1 = B0(u2)->buf0
    LDB(1, 0, b1);
    STAGE_B(0, u2, 0);
    BAR();
    MFMA_Q(0, 1, b1);
    BAR();
    // phase 2: Q11 (reuse b1) | S2 = A0(u2)->buf0
    LDA(1, 0);
    STAGE_A(0, u2, 0);
    BAR();
    MFMA_Q(1, 1, b1);
    BAR();
    // phase 3: Q10 (reuse af + b0) | S3 = B1(u2)->buf0 | vmcnt(6)
    STAGE_B(1, u2, 0);
    BAR();
    MFMA_Q(1, 0, b0);
    WAIT_VM6();
    BAR();
    // phase 4: Q00 of tile 2j+1 | S4 = A1(u2)->buf0
    LDA(0, 1); LDB(0, 1, b0);
    STAGE_A(1, u2, 0);
    BAR();
    MFMA_Q(0, 0, b0);
    BAR();
    // phase 5: Q01 | S5 = B0(u3)->buf1
    LDB(1, 1, b1);
    STAGE_B(0, u3, 1);
    BAR();
    MFMA_Q(0, 1, b1);
    BAR();
    // phase 6: Q11 | S6 = A0(u3)->buf1
    LDA(1, 1);
    STAGE_A(0, u3, 1);
    BAR();
    MFMA_Q(1, 1, b1);
    BAR();
    // phase 7: Q10 | S7 = B1(u3)->buf1 | vmcnt(6)
    STAGE_B(1, u3, 1);
    BAR();
    MFMA_Q(1, 0, b0);
    WAIT_VM6();
    BAR();
  }

  // ---- epilogue: C/D layout col=lane&15, row=(lane>>4)*4+reg ----
  const int crow = wr * 128 + lgrp * 4;
  const int ccol = wc * 64 + lrow;
#pragma unroll
  for (int mi = 0; mi < 8; ++mi)
#pragma unroll
    for (int ni = 0; ni < 4; ++ni)
#pragma unroll
      for (int r = 0; r < 4; ++r) {
        const long row = bm0 + crow + mi * 16 + r;
        const long col = bn0 + ccol + ni * 16;
        C[row * Odim + col] = acc[mi][ni][r];
      }
}

extern "C" void kernel_launch(void* const* d_in, const int* in_sizes, int n_in,
                              void* d_out, int out_size, void* d_ws, size_t ws_size,
                              hipStream_t stream) {
  const float* x = (const float*)d_in[0];    // [M,K] f32
  const int* qw = (const int*)d_in[1];       // [O,K/2] int32 (bytes)
  const float* wsc = (const float*)d_in[2];  // [K/128,O] f32
  const float* wz = (const float*)d_in[3];   // [K/128,O] f32
  float* out = (float*)d_out;                // [M,O] f32

  unsigned short* Wb = (unsigned short*)d_ws;           // O*K bf16
  unsigned short* Xb = Wb + (size_t)Odim * Kdim;        // M*K bf16

  dequant_kernel<<<2048, 256, 0, stream>>>(qw, wsc, wz, Wb);
  cvt_x_kernel<<<2048, 256, 0, stream>>>(x, Xb, (long)Mdim * Kdim / 8);

  const int nblk = (Mdim / BM) * (Odim / BN);  // 512
  gemm_kernel<<<nblk, 512, 0, stream>>>(Xb, Wb, out);
}